// Round 12
// baseline (175.448 us; speedup 1.0000x reference)
//
#include <hip/hip_runtime.h>
#include <hip/hip_bf16.h>
#include <stdint.h>

#define NHEADS 8
#define SEQ    4096
#define DIM    128
#define TOK    32768

typedef __attribute__((ext_vector_type(4)))  float  f32x4;
typedef __attribute__((ext_vector_type(16))) float  f32x16;
typedef __attribute__((ext_vector_type(8)))  short  bf16x8;
typedef __attribute__((ext_vector_type(8)))  unsigned short u16x8;
typedef __attribute__((ext_vector_type(4)))  unsigned int   u32x4;

__device__ __forceinline__ unsigned short f32_to_bf16(float f) {
  union { float f; unsigned int u; } cv; cv.f = f;
  unsigned int u = cv.u;
  u += 0x7FFFu + ((u >> 16) & 1u);   // round-to-nearest-even
  return (unsigned short)(u >> 16);
}
__device__ __forceinline__ unsigned cvtpk(float lo, float hi) {
  unsigned r;
  asm("v_cvt_pk_bf16_f32 %0, %1, %2" : "=v"(r) : "v"(lo), "v"(hi));
  return r;
}
// async global->LDS, 16B/lane; LDS dest = wave-uniform base + lane*16,
// global src per-lane (pre-swizzled source pattern, T21).
__device__ __forceinline__ void gload16(const void* g, void* l) {
  __builtin_amdgcn_global_load_lds(
      (const __attribute__((address_space(1))) unsigned int*)g,
      (__attribute__((address_space(3))) unsigned int*)l, 16, 0, 0);
}

// ---------------------------------------------------------------------------
// Kernel A0: Wt[j][k] = bf16(W[k][j])  (384x128; in the old Vh slot)
// ---------------------------------------------------------------------------
__global__ __launch_bounds__(256) void wt_prep_kernel(
    const float* __restrict__ W, unsigned short* __restrict__ Wt) {
  const int tid = threadIdx.x;
  const int j  = blockIdx.x * 32 + (tid >> 3);
  const int k0 = (tid & 7) * 16;
  u16x8 a, b;
  #pragma unroll
  for (int x = 0; x < 8; ++x) a[x] = f32_to_bf16(W[(size_t)(k0 + x) * 384 + j]);
  #pragma unroll
  for (int x = 0; x < 8; ++x) b[x] = f32_to_bf16(W[(size_t)(k0 + 8 + x) * 384 + j]);
  *reinterpret_cast<u16x8*>(Wt + (size_t)j * 128 + k0)     = a;
  *reinterpret_cast<u16x8*>(Wt + (size_t)j * 128 + k0 + 8) = b;
}

// ---------------------------------------------------------------------------
// Kernel A: MFMA qkv projection + fused V-transpose (validated r11).
// ---------------------------------------------------------------------------
__global__ __launch_bounds__(256, 2) void qkv_proj_kernel(
    const float* __restrict__ qin, const unsigned short* __restrict__ Wt,
    const float* __restrict__ bqkv, const float* __restrict__ ubias,
    const float* __restrict__ vbias,
    unsigned short* __restrict__ Qh, unsigned short* __restrict__ Kh,
    unsigned short* __restrict__ Vt) {
  __shared__ __align__(16) char Xl[16384];          // 64 tok x 128 k, swizzled
  __shared__ __align__(16) unsigned short Qb[8192]; // [h][s][e] bounce
  __shared__ __align__(16) unsigned short Vb[8192]; // [h][s][e] bounce

  const int tid  = threadIdx.x;
  const int lane = tid & 63;
  const int w    = tid >> 6;
  const int wm   = w & 1;
  const int wn   = w >> 1;
  const int col  = lane & 31;
  const int hi   = lane >> 5;
  const int tok0 = blockIdx.x * 64;
  const int s0b  = blockIdx.x * 8;     // block's s range: s0b..s0b+7

  #pragma unroll
  for (int c = 0; c < 4; ++c) {
    int idx = tid + c * 256;
    int row = idx >> 4, c16 = idx & 15;
    const float* src = qin + (size_t)(tok0 + row) * DIM + c16 * 8;
    f32x4 lo  = *reinterpret_cast<const f32x4*>(src);
    f32x4 hi4 = *reinterpret_cast<const f32x4*>(src + 4);
    u32x4 pk;
    pk[0] = cvtpk(lo[0],  lo[1]);  pk[1] = cvtpk(lo[2],  lo[3]);
    pk[2] = cvtpk(hi4[0], hi4[1]); pk[3] = cvtpk(hi4[2], hi4[3]);
    *reinterpret_cast<u32x4*>(Xl + ((row * 256 + c16 * 16) ^ ((row & 7) << 4))) = pk;
  }
  __syncthreads();

  bf16x8 af[8];
  {
    int row = wm * 32 + col;
    #pragma unroll
    for (int kk = 0; kk < 8; ++kk)
      af[kk] = *reinterpret_cast<const bf16x8*>(
          Xl + ((row * 256 + kk * 32 + hi * 16) ^ ((row & 7) << 4)));
  }

  const int s0 = s0b + wm * 4;
  const float scale = 0.1275174309f;   // log2(e)/sqrt(128)

  #pragma unroll
  for (int nt = 0; nt < 6; ++nt) {
    const int j0 = wn * 192 + nt * 32;

    const unsigned short* wp = Wt + (size_t)(j0 + col) * 128 + hi * 8;
    f32x16 acc = (f32x16)(0.0f);
    #pragma unroll
    for (int kk = 0; kk < 8; ++kk) {
      bf16x8 bf = *reinterpret_cast<const bf16x8*>(wp + kk * 16);
      acc = __builtin_amdgcn_mfma_f32_32x32x16_bf16(af[kk], bf, acc, 0, 0, 0);
    }

    const float bqv = bqkv[j0 + col];
    if (j0 < 128) {                      // Q (+u_bias, *scale) -> Qb LDS
      const int e = j0 + col;
      float ub[4];
      #pragma unroll
      for (int r = 0; r < 4; ++r) ub[r] = ubias[(r + 4 * hi) * DIM + e];
      #pragma unroll
      for (int i = 0; i < 16; ++i) {
        int h = (i & 3) + 4 * hi;
        int s = wm * 4 + (i >> 2);
        Qb[h * 1024 + s * 128 + e] = f32_to_bf16((acc[i] + bqv + ub[i & 3]) * scale);
      }
    } else if (j0 < 256) {               // K (+v_bias) -> global
      const int e = j0 - 128 + col;
      float vb[4];
      #pragma unroll
      for (int r = 0; r < 4; ++r) vb[r] = vbias[(r + 4 * hi) * DIM + e];
      #pragma unroll
      for (int i = 0; i < 16; ++i) {
        int h = (i & 3) + 4 * hi;
        Kh[((size_t)h * SEQ + s0 + (i >> 2)) * DIM + e] =
            f32_to_bf16(acc[i] + bqv + vb[i & 3]);
      }
    } else {                             // V -> Vb LDS
      const int e = j0 - 256 + col;
      #pragma unroll
      for (int i = 0; i < 16; ++i) {
        int h = (i & 3) + 4 * hi;
        int s = wm * 4 + (i >> 2);
        Vb[h * 1024 + s * 128 + e] = f32_to_bf16(acc[i] + bqv);
      }
    }
  }

  __syncthreads();   // Qb/Vb complete

  #pragma unroll
  for (int p = 0; p < 4; ++p) {
    int cid = tid + p * 256;
    int h = cid >> 7, s = (cid >> 4) & 7, ec = cid & 15;
    u16x8 v = *reinterpret_cast<const u16x8*>(&Qb[h * 1024 + s * 128 + ec * 8]);
    *reinterpret_cast<u16x8*>(Qh + ((size_t)h * SEQ + s0b + s) * DIM + ec * 8) = v;
  }
  #pragma unroll
  for (int p = 0; p < 4; ++p) {
    int cid = tid + p * 256;
    int h = cid >> 7, e = cid & 127;
    u16x8 v;
    #pragma unroll
    for (int sl = 0; sl < 8; ++sl) v[sl] = Vb[h * 1024 + sl * 128 + e];
    *reinterpret_cast<u16x8*>(Vt + ((size_t)h * DIM + e) * SEQ + s0b) = v;
  }
}

// ---------------------------------------------------------------------------
// Kernel B: flash attention (r10/r11 structure) + r12 scheduling:
//   (1) all K-frag reads + first half of V-frag reads issued BEFORE any
//       MFMA: V reads don't depend on softmax; desyncs the per-wave LDS
//       bursts (waves in exp2 overlap other waves' reads) and gives the
//       compiler a deep lgkm queue for fine-grained counting.
//   (2) QK dependent-MFMA chain split 8 -> 2x4 (sa/sb + vector add).
// ---------------------------------------------------------------------------
__global__ __launch_bounds__(768, 3) void attn_fwd_kernel(
    const unsigned short* __restrict__ Qh, const unsigned short* __restrict__ Kh,
    const unsigned short* __restrict__ Vt, float* __restrict__ Out) {
  __shared__ __align__(16) char smem[134656];
  float* lbuf = reinterpret_cast<float*>(smem + 131072);   // [12][64]
  float* linv = reinterpret_cast<float*>(smem + 134144);   // [4][32]

  const int tid  = threadIdx.x;
  const int lane = tid & 63;
  const int w    = tid >> 6;        // 0..11
  const int g    = w >> 2;          // key-shard group 0..2
  const int wq   = w & 3;           // q-subtile within group
  const int col  = lane & 31;
  const int hi   = lane >> 5;
  const int h    = blockIdx.x & 7;  // head-per-XCD
  const int qb   = blockIdx.x >> 3;
  const int q0   = qb * 128 + wq * 32;

  const int tbase = g * 43;                 // tile shard start
  const int nt    = (g == 2) ? 42 : 43;     // 43+43+42 = 128 tiles of 32 keys

  char* Kg = smem + g * 16384;              // 2 bufs x 8192
  char* Vg = smem + 49152 + g * 20480;      // 2 bufs x 10240 (stride-80 rows)

  // Q fragments (B-operand)
  bf16x8 qf[8];
  const unsigned short* qp = Qh + ((size_t)h * SEQ + q0 + col) * DIM + hi * 8;
  #pragma unroll
  for (int kk = 0; kk < 8; ++kk)
    qf[kk] = *reinterpret_cast<const bf16x8*>(qp + kk * 16);

  f32x16 acc[4];
  #pragma unroll
  for (int n = 0; n < 4; ++n) acc[n] = (f32x16)(0.0f);
  float l_r = 0.0f;

  // ---- precomputed LDS read bases ----
  const int c3 = (col >> 1) & 3;
  const char* kpre[4];
  #pragma unroll
  for (int j = 0; j < 4; ++j)
    kpre[j] = Kg + col * 256 + ((hi ^ (col & 1)) << 4) + ((j ^ c3) << 5);
  const char* vb = Vg + col * 80 + hi * 16;

  // ---- staging source offsets (fixed per lane) ----
  int kofs[2];
  #pragma unroll
  for (int c2 = 0; c2 < 2; ++c2) {
    int c   = wq * 2 + c2;
    int row = c * 4 + (lane >> 4);
    kofs[c2] = row * 256 + ((((lane & 15) ^ (row & 7)) << 4));
  }
  int vofs[3];
  #pragma unroll
  for (int c2 = 0; c2 < 3; ++c2) {
    int c     = wq + 4 * c2;
    int laddr = c * 1024 + lane * 16;
    int row   = laddr / 80;
    int unit  = (laddr - row * 80) >> 4;
    vofs[c2]  = row * (SEQ * 2) + (unit < 4 ? unit * 16 : 0);
  }

  const char* KbaseB = reinterpret_cast<const char*>(Kh + (size_t)h * SEQ * DIM);
  const char* VbaseB = reinterpret_cast<const char*>(Vt + (size_t)h * DIM * SEQ);

  auto stage = [&](int tl, int buf) {
    const char* ks = KbaseB + (size_t)(tbase + tl) * 8192;   // 32 keys * 256B
    #pragma unroll
    for (int c2 = 0; c2 < 2; ++c2)
      gload16(ks + kofs[c2], Kg + buf * 8192 + (wq * 2 + c2) * 1024);
    const char* vs = VbaseB + (size_t)(tbase + tl) * 64;     // 32 keys * 2B
    #pragma unroll
    for (int c2 = 0; c2 < 3; ++c2) {
      int c = wq + 4 * c2;
      if (c < 10)
        gload16(vs + vofs[c2], Vg + buf * 10240 + c * 1024);
    }
  };

  auto compute = [&](int cur) {   // cur is a literal at every call site
    // (1) issue K reads + first-half V reads before any MFMA
    bf16x8 kf[8];
    #pragma unroll
    for (int kk = 0; kk < 8; ++kk)
      kf[kk] = *reinterpret_cast<const bf16x8*>(
          kpre[kk & 3] + cur * 8192 + (kk >> 2) * 128);
    bf16x8 vf0[2], vf1[2];
    #pragma unroll
    for (int ks = 0; ks < 2; ++ks) {
      vf0[ks] = *reinterpret_cast<const bf16x8*>(vb + cur * 10240 + ks * 32);
      vf1[ks] = *reinterpret_cast<const bf16x8*>(vb + cur * 10240 + 2560 + ks * 32);
    }

    // (2) QK split into two independent 4-chains
    f32x16 sa = (f32x16)(0.0f), sb = (f32x16)(0.0f);
    __builtin_amdgcn_s_setprio(1);
    #pragma unroll
    for (int kk = 0; kk < 4; ++kk)
      sa = __builtin_amdgcn_mfma_f32_32x32x16_bf16(kf[kk], qf[kk], sa, 0, 0, 0);
    #pragma unroll
    for (int kk = 4; kk < 8; ++kk)
      sb = __builtin_amdgcn_mfma_f32_32x32x16_bf16(kf[kk], qf[kk], sb, 0, 0, 0);
    __builtin_amdgcn_s_setprio(0);
    f32x16 sc = sa + sb;

    // ---- P = exp2(S): no max needed (cannot overflow) ----
    bf16x8 pa[2];
    #pragma unroll
    for (int s16 = 0; s16 < 2; ++s16) {
      float p8[8];
      #pragma unroll
      for (int i = 0; i < 8; ++i) {
        p8[i] = exp2f(sc[s16 * 8 + i]);
        l_r += p8[i];
      }
      unsigned A = cvtpk(p8[0], p8[1]);   // low pair first (validated r4)
      unsigned B = cvtpk(p8[4], p8[5]);
      asm("v_permlane32_swap_b32 %0, %1" : "+v"(A), "+v"(B));
      unsigned C = cvtpk(p8[2], p8[3]);
      unsigned D = cvtpk(p8[6], p8[7]);
      asm("v_permlane32_swap_b32 %0, %1" : "+v"(C), "+v"(D));
      u32x4 wd; wd[0] = A; wd[1] = C; wd[2] = B; wd[3] = D;
      pa[s16] = *reinterpret_cast<bf16x8*>(&wd);
    }

    // ---- PV: acc[n] += P(32q x 32k) @ V(32k x 32e) ----
    __builtin_amdgcn_s_setprio(1);
    #pragma unroll
    for (int ks = 0; ks < 2; ++ks) {
      acc[0] = __builtin_amdgcn_mfma_f32_32x32x16_bf16(pa[ks], vf0[ks], acc[0], 0, 0, 0);
      acc[1] = __builtin_amdgcn_mfma_f32_32x32x16_bf16(pa[ks], vf1[ks], acc[1], 0, 0, 0);
    }
    __builtin_amdgcn_s_setprio(0);
    bf16x8 vf2[2], vf3[2];
    #pragma unroll
    for (int ks = 0; ks < 2; ++ks) {
      vf2[ks] = *reinterpret_cast<const bf16x8*>(vb + cur * 10240 + 5120 + ks * 32);
      vf3[ks] = *reinterpret_cast<const bf16x8*>(vb + cur * 10240 + 7680 + ks * 32);
    }
    __builtin_amdgcn_s_setprio(1);
    #pragma unroll
    for (int ks = 0; ks < 2; ++ks) {
      acc[2] = __builtin_amdgcn_mfma_f32_32x32x16_bf16(pa[ks], vf2[ks], acc[2], 0, 0, 0);
      acc[3] = __builtin_amdgcn_mfma_f32_32x32x16_bf16(pa[ks], vf3[ks], acc[3], 0, 0, 0);
    }
    __builtin_amdgcn_s_setprio(0);
  };

  // ---- pipeline: tile t lives in buffer t&1 ----
  stage(0, 0);
  __syncthreads();                    // tile 0 resident

  stage(1, 1);                        // t = 0
  compute(0);
  __syncthreads();

  for (int t2 = 0; t2 < 21; ++t2) {
    const int t = 2 * t2 + 1;         // odd tile -> buf1
    if (t + 1 < nt) stage(t + 1, 0);
    compute(1);
    __syncthreads();
    if (t + 2 < nt) stage(t + 2, 1);
    if (t + 1 < nt) compute(0);
    __syncthreads();
  }

  // ---- merge: pure add; g1 -> slots 0-3, g2 -> slots 4-7 ----
  lbuf[w * 64 + lane] = l_r;
  if (g > 0) {
    char* mb = smem + ((g - 1) * 4 + wq) * 16384;
    #pragma unroll
    for (int n = 0; n < 4; ++n)
      #pragma unroll
      for (int i = 0; i < 4; ++i) {
        f32x4 v;
        v[0] = acc[n][4 * i + 0]; v[1] = acc[n][4 * i + 1];
        v[2] = acc[n][4 * i + 2]; v[3] = acc[n][4 * i + 3];
        *reinterpret_cast<f32x4*>(mb + (n * 4 + i) * 1024 + lane * 16) = v;
      }
  }
  __syncthreads();
  if (g == 0) {
    #pragma unroll
    for (int s = 0; s < 2; ++s) {
      const char* mb = smem + (s * 4 + wq) * 16384;
      #pragma unroll
      for (int n = 0; n < 4; ++n)
        #pragma unroll
        for (int i = 0; i < 4; ++i) {
          f32x4 v = *reinterpret_cast<const f32x4*>(mb + (n * 4 + i) * 1024 + lane * 16);
          acc[n][4 * i + 0] += v[0]; acc[n][4 * i + 1] += v[1];
          acc[n][4 * i + 2] += v[2]; acc[n][4 * i + 3] += v[3];
        }
    }
    float ltot = 0.0f;
    #pragma unroll
    for (int gg = 0; gg < 3; ++gg)
      ltot += lbuf[(gg * 4 + wq) * 64 + col] + lbuf[(gg * 4 + wq) * 64 + col + 32];
    linv[wq * 32 + col] = 1.0f / ltot;
    asm volatile("s_waitcnt lgkmcnt(0)" ::: "memory");

    float* op = Out + ((size_t)h * SEQ + q0) * DIM + col;
    #pragma unroll
    for (int g2 = 0; g2 < 4; ++g2) {
      f32x4 iv = *reinterpret_cast<f32x4*>(&linv[wq * 32 + 8 * g2 + 4 * hi]);
      #pragma unroll
      for (int n = 0; n < 4; ++n)
        #pragma unroll
        for (int i = 0; i < 4; ++i)
          op[(size_t)(8 * g2 + 4 * hi + i) * DIM + n * 32] =
              acc[n][4 * g2 + i] * iv[i];
    }
  }
}

// ---------------------------------------------------------------------------
extern "C" void kernel_launch(void* const* d_in, const int* in_sizes, int n_in,
                              void* d_out, int out_size, void* d_ws, size_t ws_size,
                              hipStream_t stream) {
  (void)in_sizes; (void)n_in; (void)out_size; (void)ws_size;
  const float* query = (const float*)d_in[0];
  const float* W_qkv = (const float*)d_in[3];
  const float* b_qkv = (const float*)d_in[4];
  const float* u_bias = (const float*)d_in[5];
  const float* v_bias = (const float*)d_in[6];
  float* out = (float*)d_out;

  const size_t per = (size_t)NHEADS * SEQ * DIM;   // 4M elems
  unsigned short* Qh = (unsigned short*)d_ws;
  unsigned short* Kh = Qh + per;
  unsigned short* Wt = Kh + per;      // old Vh slot — not aliasing Vt
  unsigned short* Vt = Wt + per;      // proj writes Vt directly

  wt_prep_kernel<<<dim3(12), dim3(256), 0, stream>>>(W_qkv, Wt);
  qkv_proj_kernel<<<dim3(TOK / 64), dim3(256), 0, stream>>>(
      query, Wt, b_qkv, u_bias, v_bias, Qh, Kh, Vt);
  attn_fwd_kernel<<<dim3(NHEADS * 32), dim3(768), 0, stream>>>(Qh, Kh, Vt, out);
}

// Round 13
// 117.937 us; speedup vs baseline: 1.4876x; 1.4876x over previous
//
#include <hip/hip_runtime.h>
#include <hip/hip_bf16.h>
#include <stdint.h>

#define NHEADS 8
#define SEQ    4096
#define DIM    128
#define TOK    32768

typedef __attribute__((ext_vector_type(4)))  float  f32x4;
typedef __attribute__((ext_vector_type(16))) float  f32x16;
typedef __attribute__((ext_vector_type(8)))  short  bf16x8;
typedef __attribute__((ext_vector_type(8)))  unsigned short u16x8;
typedef __attribute__((ext_vector_type(4)))  unsigned int   u32x4;

__device__ __forceinline__ unsigned short f32_to_bf16(float f) {
  union { float f; unsigned int u; } cv; cv.f = f;
  unsigned int u = cv.u;
  u += 0x7FFFu + ((u >> 16) & 1u);   // round-to-nearest-even
  return (unsigned short)(u >> 16);
}
__device__ __forceinline__ unsigned cvtpk(float lo, float hi) {
  unsigned r;
  asm("v_cvt_pk_bf16_f32 %0, %1, %2" : "=v"(r) : "v"(lo), "v"(hi));
  return r;
}
// async global->LDS, 16B/lane; LDS dest = wave-uniform base + lane*16,
// global src per-lane (pre-swizzled source pattern, T21).
__device__ __forceinline__ void gload16(const void* g, void* l) {
  __builtin_amdgcn_global_load_lds(
      (const __attribute__((address_space(1))) unsigned int*)g,
      (__attribute__((address_space(3))) unsigned int*)l, 16, 0, 0);
}

// ---------------------------------------------------------------------------
// Kernel A0: Wt[j][k] = bf16(W[k][j])  (384x128; in the old Vh slot)
// ---------------------------------------------------------------------------
__global__ __launch_bounds__(256) void wt_prep_kernel(
    const float* __restrict__ W, unsigned short* __restrict__ Wt) {
  const int tid = threadIdx.x;
  const int j  = blockIdx.x * 32 + (tid >> 3);
  const int k0 = (tid & 7) * 16;
  u16x8 a, b;
  #pragma unroll
  for (int x = 0; x < 8; ++x) a[x] = f32_to_bf16(W[(size_t)(k0 + x) * 384 + j]);
  #pragma unroll
  for (int x = 0; x < 8; ++x) b[x] = f32_to_bf16(W[(size_t)(k0 + 8 + x) * 384 + j]);
  *reinterpret_cast<u16x8*>(Wt + (size_t)j * 128 + k0)     = a;
  *reinterpret_cast<u16x8*>(Wt + (size_t)j * 128 + k0 + 8) = b;
}

// ---------------------------------------------------------------------------
// Kernel A: MFMA qkv projection + fused V-transpose (validated r11).
// ---------------------------------------------------------------------------
__global__ __launch_bounds__(256, 2) void qkv_proj_kernel(
    const float* __restrict__ qin, const unsigned short* __restrict__ Wt,
    const float* __restrict__ bqkv, const float* __restrict__ ubias,
    const float* __restrict__ vbias,
    unsigned short* __restrict__ Qh, unsigned short* __restrict__ Kh,
    unsigned short* __restrict__ Vt) {
  __shared__ __align__(16) char Xl[16384];          // 64 tok x 128 k, swizzled
  __shared__ __align__(16) unsigned short Qb[8192]; // [h][s][e] bounce
  __shared__ __align__(16) unsigned short Vb[8192]; // [h][s][e] bounce

  const int tid  = threadIdx.x;
  const int lane = tid & 63;
  const int w    = tid >> 6;
  const int wm   = w & 1;
  const int wn   = w >> 1;
  const int col  = lane & 31;
  const int hi   = lane >> 5;
  const int tok0 = blockIdx.x * 64;
  const int s0b  = blockIdx.x * 8;     // block's s range: s0b..s0b+7

  #pragma unroll
  for (int c = 0; c < 4; ++c) {
    int idx = tid + c * 256;
    int row = idx >> 4, c16 = idx & 15;
    const float* src = qin + (size_t)(tok0 + row) * DIM + c16 * 8;
    f32x4 lo  = *reinterpret_cast<const f32x4*>(src);
    f32x4 hi4 = *reinterpret_cast<const f32x4*>(src + 4);
    u32x4 pk;
    pk[0] = cvtpk(lo[0],  lo[1]);  pk[1] = cvtpk(lo[2],  lo[3]);
    pk[2] = cvtpk(hi4[0], hi4[1]); pk[3] = cvtpk(hi4[2], hi4[3]);
    *reinterpret_cast<u32x4*>(Xl + ((row * 256 + c16 * 16) ^ ((row & 7) << 4))) = pk;
  }
  __syncthreads();

  bf16x8 af[8];
  {
    int row = wm * 32 + col;
    #pragma unroll
    for (int kk = 0; kk < 8; ++kk)
      af[kk] = *reinterpret_cast<const bf16x8*>(
          Xl + ((row * 256 + kk * 32 + hi * 16) ^ ((row & 7) << 4)));
  }

  const int s0 = s0b + wm * 4;
  const float scale = 0.1275174309f;   // log2(e)/sqrt(128)

  #pragma unroll
  for (int nt = 0; nt < 6; ++nt) {
    const int j0 = wn * 192 + nt * 32;

    const unsigned short* wp = Wt + (size_t)(j0 + col) * 128 + hi * 8;
    f32x16 acc = (f32x16)(0.0f);
    #pragma unroll
    for (int kk = 0; kk < 8; ++kk) {
      bf16x8 bf = *reinterpret_cast<const bf16x8*>(wp + kk * 16);
      acc = __builtin_amdgcn_mfma_f32_32x32x16_bf16(af[kk], bf, acc, 0, 0, 0);
    }

    const float bqv = bqkv[j0 + col];
    if (j0 < 128) {                      // Q (+u_bias, *scale) -> Qb LDS
      const int e = j0 + col;
      float ub[4];
      #pragma unroll
      for (int r = 0; r < 4; ++r) ub[r] = ubias[(r + 4 * hi) * DIM + e];
      #pragma unroll
      for (int i = 0; i < 16; ++i) {
        int h = (i & 3) + 4 * hi;
        int s = wm * 4 + (i >> 2);
        Qb[h * 1024 + s * 128 + e] = f32_to_bf16((acc[i] + bqv + ub[i & 3]) * scale);
      }
    } else if (j0 < 256) {               // K (+v_bias) -> global
      const int e = j0 - 128 + col;
      float vb[4];
      #pragma unroll
      for (int r = 0; r < 4; ++r) vb[r] = vbias[(r + 4 * hi) * DIM + e];
      #pragma unroll
      for (int i = 0; i < 16; ++i) {
        int h = (i & 3) + 4 * hi;
        Kh[((size_t)h * SEQ + s0 + (i >> 2)) * DIM + e] =
            f32_to_bf16(acc[i] + bqv + vb[i & 3]);
      }
    } else {                             // V -> Vb LDS
      const int e = j0 - 256 + col;
      #pragma unroll
      for (int i = 0; i < 16; ++i) {
        int h = (i & 3) + 4 * hi;
        int s = wm * 4 + (i >> 2);
        Vb[h * 1024 + s * 128 + e] = f32_to_bf16(acc[i] + bqv);
      }
    }
  }

  __syncthreads();   // Qb/Vb complete

  #pragma unroll
  for (int p = 0; p < 4; ++p) {
    int cid = tid + p * 256;
    int h = cid >> 7, s = (cid >> 4) & 7, ec = cid & 15;
    u16x8 v = *reinterpret_cast<const u16x8*>(&Qb[h * 1024 + s * 128 + ec * 8]);
    *reinterpret_cast<u16x8*>(Qh + ((size_t)h * SEQ + s0b + s) * DIM + ec * 8) = v;
  }
  #pragma unroll
  for (int p = 0; p < 4; ++p) {
    int cid = tid + p * 256;
    int h = cid >> 7, e = cid & 127;
    u16x8 v;
    #pragma unroll
    for (int sl = 0; sl < 8; ++sl) v[sl] = Vb[h * 1024 + sl * 128 + e];
    *reinterpret_cast<u16x8*>(Vt + ((size_t)h * DIM + e) * SEQ + s0b) = v;
  }
}

// ---------------------------------------------------------------------------
// Kernel B: flash attention (r11 exact revert — validated 95.5us):
// split-K x3, 12 waves = 3/SIMD, global_load_lds staging with pre-swizzled
// sources, no softmax max (exp2(S) cannot overflow), fixed-VGPR+immediate
// LDS reads, inline fragment reads (r12 lesson: hoisting spills at the
// 3-wave register cap — do NOT extend live ranges here).
// ---------------------------------------------------------------------------
__global__ __launch_bounds__(768, 3) void attn_fwd_kernel(
    const unsigned short* __restrict__ Qh, const unsigned short* __restrict__ Kh,
    const unsigned short* __restrict__ Vt, float* __restrict__ Out) {
  __shared__ __align__(16) char smem[134656];
  float* lbuf = reinterpret_cast<float*>(smem + 131072);   // [12][64]
  float* linv = reinterpret_cast<float*>(smem + 134144);   // [4][32]

  const int tid  = threadIdx.x;
  const int lane = tid & 63;
  const int w    = tid >> 6;        // 0..11
  const int g    = w >> 2;          // key-shard group 0..2
  const int wq   = w & 3;           // q-subtile within group
  const int col  = lane & 31;
  const int hi   = lane >> 5;
  const int h    = blockIdx.x & 7;  // head-per-XCD
  const int qb   = blockIdx.x >> 3;
  const int q0   = qb * 128 + wq * 32;

  const int tbase = g * 43;                 // tile shard start
  const int nt    = (g == 2) ? 42 : 43;     // 43+43+42 = 128 tiles of 32 keys

  char* Kg = smem + g * 16384;              // 2 bufs x 8192
  char* Vg = smem + 49152 + g * 20480;      // 2 bufs x 10240 (stride-80 rows)

  // Q fragments (B-operand)
  bf16x8 qf[8];
  const unsigned short* qp = Qh + ((size_t)h * SEQ + q0 + col) * DIM + hi * 8;
  #pragma unroll
  for (int kk = 0; kk < 8; ++kk)
    qf[kk] = *reinterpret_cast<const bf16x8*>(qp + kk * 16);

  f32x16 acc[4];
  #pragma unroll
  for (int n = 0; n < 4; ++n) acc[n] = (f32x16)(0.0f);
  float l_r = 0.0f;

  // ---- precomputed LDS read bases ----
  const int c3 = (col >> 1) & 3;
  const char* kpre[4];
  #pragma unroll
  for (int j = 0; j < 4; ++j)
    kpre[j] = Kg + col * 256 + ((hi ^ (col & 1)) << 4) + ((j ^ c3) << 5);
  const char* vb = Vg + col * 80 + hi * 16;

  // ---- staging source offsets (fixed per lane) ----
  int kofs[2];
  #pragma unroll
  for (int c2 = 0; c2 < 2; ++c2) {
    int c   = wq * 2 + c2;
    int row = c * 4 + (lane >> 4);
    kofs[c2] = row * 256 + ((((lane & 15) ^ (row & 7)) << 4));
  }
  int vofs[3];
  #pragma unroll
  for (int c2 = 0; c2 < 3; ++c2) {
    int c     = wq + 4 * c2;
    int laddr = c * 1024 + lane * 16;
    int row   = laddr / 80;
    int unit  = (laddr - row * 80) >> 4;
    vofs[c2]  = row * (SEQ * 2) + (unit < 4 ? unit * 16 : 0);
  }

  const char* KbaseB = reinterpret_cast<const char*>(Kh + (size_t)h * SEQ * DIM);
  const char* VbaseB = reinterpret_cast<const char*>(Vt + (size_t)h * DIM * SEQ);

  auto stage = [&](int tl, int buf) {
    const char* ks = KbaseB + (size_t)(tbase + tl) * 8192;   // 32 keys * 256B
    #pragma unroll
    for (int c2 = 0; c2 < 2; ++c2)
      gload16(ks + kofs[c2], Kg + buf * 8192 + (wq * 2 + c2) * 1024);
    const char* vs = VbaseB + (size_t)(tbase + tl) * 64;     // 32 keys * 2B
    #pragma unroll
    for (int c2 = 0; c2 < 3; ++c2) {
      int c = wq + 4 * c2;
      if (c < 10)
        gload16(vs + vofs[c2], Vg + buf * 10240 + c * 1024);
    }
  };

  auto compute = [&](int cur) {   // cur is a literal at every call site
    f32x16 sc = (f32x16)(0.0f);
    __builtin_amdgcn_s_setprio(1);
    #pragma unroll
    for (int kk = 0; kk < 8; ++kk) {
      bf16x8 kf = *reinterpret_cast<const bf16x8*>(
          kpre[kk & 3] + cur * 8192 + (kk >> 2) * 128);
      sc = __builtin_amdgcn_mfma_f32_32x32x16_bf16(kf, qf[kk], sc, 0, 0, 0);
    }
    __builtin_amdgcn_s_setprio(0);

    bf16x8 pa[2];
    #pragma unroll
    for (int s16 = 0; s16 < 2; ++s16) {
      float p8[8];
      #pragma unroll
      for (int i = 0; i < 8; ++i) {
        p8[i] = exp2f(sc[s16 * 8 + i]);
        l_r += p8[i];
      }
      unsigned A = cvtpk(p8[0], p8[1]);   // low pair first (validated r4)
      unsigned B = cvtpk(p8[4], p8[5]);
      asm("v_permlane32_swap_b32 %0, %1" : "+v"(A), "+v"(B));
      unsigned C = cvtpk(p8[2], p8[3]);
      unsigned D = cvtpk(p8[6], p8[7]);
      asm("v_permlane32_swap_b32 %0, %1" : "+v"(C), "+v"(D));
      u32x4 wd; wd[0] = A; wd[1] = C; wd[2] = B; wd[3] = D;
      pa[s16] = *reinterpret_cast<bf16x8*>(&wd);
    }

    bf16x8 vf0[2], vf1[2];
    #pragma unroll
    for (int ks = 0; ks < 2; ++ks) {
      vf0[ks] = *reinterpret_cast<const bf16x8*>(vb + cur * 10240 + ks * 32);
      vf1[ks] = *reinterpret_cast<const bf16x8*>(vb + cur * 10240 + 2560 + ks * 32);
    }
    __builtin_amdgcn_s_setprio(1);
    #pragma unroll
    for (int ks = 0; ks < 2; ++ks) {
      acc[0] = __builtin_amdgcn_mfma_f32_32x32x16_bf16(pa[ks], vf0[ks], acc[0], 0, 0, 0);
      acc[1] = __builtin_amdgcn_mfma_f32_32x32x16_bf16(pa[ks], vf1[ks], acc[1], 0, 0, 0);
    }
    __builtin_amdgcn_s_setprio(0);
    #pragma unroll
    for (int ks = 0; ks < 2; ++ks) {
      vf0[ks] = *reinterpret_cast<const bf16x8*>(vb + cur * 10240 + 5120 + ks * 32);
      vf1[ks] = *reinterpret_cast<const bf16x8*>(vb + cur * 10240 + 7680 + ks * 32);
    }
    __builtin_amdgcn_s_setprio(1);
    #pragma unroll
    for (int ks = 0; ks < 2; ++ks) {
      acc[2] = __builtin_amdgcn_mfma_f32_32x32x16_bf16(pa[ks], vf0[ks], acc[2], 0, 0, 0);
      acc[3] = __builtin_amdgcn_mfma_f32_32x32x16_bf16(pa[ks], vf1[ks], acc[3], 0, 0, 0);
    }
    __builtin_amdgcn_s_setprio(0);
  };

  // ---- pipeline: tile t lives in buffer t&1 ----
  stage(0, 0);
  __syncthreads();                    // tile 0 resident

  stage(1, 1);                        // t = 0
  compute(0);
  __syncthreads();

  for (int t2 = 0; t2 < 21; ++t2) {
    const int t = 2 * t2 + 1;         // odd tile -> buf1
    if (t + 1 < nt) stage(t + 1, 0);
    compute(1);
    __syncthreads();
    if (t + 2 < nt) stage(t + 2, 1);
    if (t + 1 < nt) compute(0);
    __syncthreads();
  }

  // ---- merge: pure add; g1 -> slots 0-3, g2 -> slots 4-7 ----
  lbuf[w * 64 + lane] = l_r;
  if (g > 0) {
    char* mb = smem + ((g - 1) * 4 + wq) * 16384;
    #pragma unroll
    for (int n = 0; n < 4; ++n)
      #pragma unroll
      for (int i = 0; i < 4; ++i) {
        f32x4 v;
        v[0] = acc[n][4 * i + 0]; v[1] = acc[n][4 * i + 1];
        v[2] = acc[n][4 * i + 2]; v[3] = acc[n][4 * i + 3];
        *reinterpret_cast<f32x4*>(mb + (n * 4 + i) * 1024 + lane * 16) = v;
      }
  }
  __syncthreads();
  if (g == 0) {
    #pragma unroll
    for (int s = 0; s < 2; ++s) {
      const char* mb = smem + (s * 4 + wq) * 16384;
      #pragma unroll
      for (int n = 0; n < 4; ++n)
        #pragma unroll
        for (int i = 0; i < 4; ++i) {
          f32x4 v = *reinterpret_cast<const f32x4*>(mb + (n * 4 + i) * 1024 + lane * 16);
          acc[n][4 * i + 0] += v[0]; acc[n][4 * i + 1] += v[1];
          acc[n][4 * i + 2] += v[2]; acc[n][4 * i + 3] += v[3];
        }
    }
    float ltot = 0.0f;
    #pragma unroll
    for (int gg = 0; gg < 3; ++gg)
      ltot += lbuf[(gg * 4 + wq) * 64 + col] + lbuf[(gg * 4 + wq) * 64 + col + 32];
    linv[wq * 32 + col] = 1.0f / ltot;
    asm volatile("s_waitcnt lgkmcnt(0)" ::: "memory");

    float* op = Out + ((size_t)h * SEQ + q0) * DIM + col;
    #pragma unroll
    for (int g2 = 0; g2 < 4; ++g2) {
      f32x4 iv = *reinterpret_cast<f32x4*>(&linv[wq * 32 + 8 * g2 + 4 * hi]);
      #pragma unroll
      for (int n = 0; n < 4; ++n)
        #pragma unroll
        for (int i = 0; i < 4; ++i)
          op[(size_t)(8 * g2 + 4 * hi + i) * DIM + n * 32] =
              acc[n][4 * g2 + i] * iv[i];
    }
  }
}

// ---------------------------------------------------------------------------
extern "C" void kernel_launch(void* const* d_in, const int* in_sizes, int n_in,
                              void* d_out, int out_size, void* d_ws, size_t ws_size,
                              hipStream_t stream) {
  (void)in_sizes; (void)n_in; (void)out_size; (void)ws_size;
  const float* query = (const float*)d_in[0];
  const float* W_qkv = (const float*)d_in[3];
  const float* b_qkv = (const float*)d_in[4];
  const float* u_bias = (const float*)d_in[5];
  const float* v_bias = (const float*)d_in[6];
  float* out = (float*)d_out;

  const size_t per = (size_t)NHEADS * SEQ * DIM;   // 4M elems
  unsigned short* Qh = (unsigned short*)d_ws;
  unsigned short* Kh = Qh + per;
  unsigned short* Wt = Kh + per;      // old Vh slot — not aliasing Vt
  unsigned short* Vt = Wt + per;      // proj writes Vt directly

  wt_prep_kernel<<<dim3(12), dim3(256), 0, stream>>>(W_qkv, Wt);
  qkv_proj_kernel<<<dim3(TOK / 64), dim3(256), 0, stream>>>(
      query, Wt, b_qkv, u_bias, v_bias, Qh, Kh, Vt);
  attn_fwd_kernel<<<dim3(NHEADS * 32), dim3(768), 0, stream>>>(Qh, Kh, Vt, out);
}